// Round 3
// baseline (1188.323 us; speedup 1.0000x reference)
//
#include <hip/hip_runtime.h>
#include <hip/hip_bf16.h>

typedef __bf16 bf16x8 __attribute__((ext_vector_type(8)));
typedef float  f32x4  __attribute__((ext_vector_type(4)));

#define BN_EPS 1e-5f

// Per-image activation bytes (NHWC, padded 30x30):
//   act1: 900*32*2 = 57600 B, act2: 900*64*2 = 115200 B, act3: 900*128*2 = 230400 B
constexpr size_t ACT_PER_IMG = 57600 + 115200 + 230400;      // 403200
constexpr size_t SZ_POOL = (size_t)1024 * 128 * 4;           // 524288
constexpr size_t SZ_W2   = (size_t)9 * 64 * 32 * 2;          // 36864
constexpr size_t SZ_W3   = (size_t)9 * 128 * 64 * 2;         // 147456
constexpr size_t SZ_W4   = (size_t)9 * 128 * 128 * 2;        // 294912
constexpr size_t SZ_BN   = 704 * 4;                          // 2816
constexpr size_t SZ_FIXED = SZ_POOL + SZ_W2 + SZ_W3 + SZ_W4 + SZ_BN;

__device__ __forceinline__ unsigned pack2(float a, float b) {
    __hip_bfloat162 h = __float22bfloat162_rn(make_float2(a, b));
    union { __hip_bfloat162 h2; unsigned u; } u;
    u.h2 = h;
    return u.u;
}

// ---------------- prep: weight transform + BN fold ----------------
struct PrepArgs {
    const float *w2, *w3, *w4;
    const float *g1, *b1, *m1, *v1;
    const float *g2, *b2, *m2, *v2;
    const float *g3, *b3, *m3, *v3;
    const float *g4, *b4, *m4, *v4;
    __hip_bfloat16 *W2, *W3, *W4;
    float *bn; // s1[32],sh1[32], s2[64],sh2[64], s3[128],sh3[128], s4[128],sh4[128]
};

__global__ __launch_bounds__(256) void prep_k(PrepArgs a) {
    int idx = blockIdx.x * 256 + threadIdx.x;
    if (idx < 18432) { // W2'[t][o][i] = w2[o][i][t]
        int i = idx & 31; int r = idx >> 5; int o = r & 63; int t = r >> 6;
        a.W2[idx] = __float2bfloat16(a.w2[(o * 32 + i) * 9 + t]);
        return;
    }
    idx -= 18432;
    if (idx < 73728) { // W3'[t][o][i] = w3[o][i][t]
        int i = idx & 63; int r = idx >> 6; int o = r & 127; int t = r >> 7;
        a.W3[idx] = __float2bfloat16(a.w3[(o * 64 + i) * 9 + t]);
        return;
    }
    idx -= 73728;
    if (idx < 147456) { // W4'[t][o][i] = w4[o][i][t]
        int i = idx & 127; int r = idx >> 7; int o = r & 127; int t = r >> 7;
        a.W4[idx] = __float2bfloat16(a.w4[(o * 128 + i) * 9 + t]);
        return;
    }
    idx -= 147456;
    if (idx < 352) {
        const float *g, *bb, *mm, *vv; int c, so, cn;
        if (idx < 32)       { g = a.g1; bb = a.b1; mm = a.m1; vv = a.v1; c = idx;       so = 0;   cn = 32;  }
        else if (idx < 96)  { g = a.g2; bb = a.b2; mm = a.m2; vv = a.v2; c = idx - 32;  so = 64;  cn = 64;  }
        else if (idx < 224) { g = a.g3; bb = a.b3; mm = a.m3; vv = a.v3; c = idx - 96;  so = 192; cn = 128; }
        else                { g = a.g4; bb = a.b4; mm = a.m4; vv = a.v4; c = idx - 224; so = 448; cn = 128; }
        float s = g[c] * rsqrtf(vv[c] + BN_EPS);
        a.bn[so + c] = s;
        a.bn[so + cn + c] = bb[c] - mm[c] * s;
    }
}

// ---------------- kernel 1: offsets + deform sample + DCN + BN1 ----------------
__global__ __launch_bounds__(256) void deform_k(
    const float* __restrict__ x, const float* __restrict__ w_off,
    const float* __restrict__ b_off, const float* __restrict__ w_dcn,
    const float* __restrict__ b_dcn, const float* __restrict__ bn,
    __hip_bfloat16* __restrict__ act1, __hip_bfloat16* __restrict__ act2,
    __hip_bfloat16* __restrict__ act3, float* __restrict__ pooled, int b0)
{
    const int lb = blockIdx.x;        // chunk-local image
    const int b  = b0 + lb;           // global image (x, pooled indexing)
    const int tid = threadIdx.x;
    __shared__ float xp[900];                  // padded 30x30 input image
    __shared__ float sw[564];
    float* swo = sw;        // 162: w_off
    float* sbo = sw + 162;  // 18:  b_off
    float* swd = sw + 180;  // 288: w_dcn
    float* sbd = sw + 468;  // 32:  b_dcn
    float* ss1 = sw + 500;  // 32:  bn1 scale
    float* ssh = sw + 532;  // 32:  bn1 shift

    for (int i = tid; i < 900; i += 256) {
        int y = i / 30, xc = i % 30;
        float v = 0.f;
        if (y >= 1 && y <= 28 && xc >= 1 && xc <= 28)
            v = x[(size_t)b * 784 + (y - 1) * 28 + (xc - 1)];
        xp[i] = v;
    }
    for (int i = tid; i < 564; i += 256) {
        float v;
        if (i < 162)      v = w_off[i];
        else if (i < 180) v = b_off[i - 162];
        else if (i < 468) v = w_dcn[i - 180];
        else if (i < 500) v = b_dcn[i - 468];
        else if (i < 532) v = bn[i - 500];
        else              v = bn[32 + (i - 532)];
        sw[i] = v;
    }
    if (tid < 128) pooled[b * 128 + tid] = 0.f;
    __syncthreads();

    for (int p = tid; p < 784; p += 256) {
        int y = p / 28, xx = p % 28;
        float off[18];
        #pragma unroll
        for (int o = 0; o < 18; o++) off[o] = sbo[o];
        #pragma unroll
        for (int ty = 0; ty < 3; ty++)
            #pragma unroll
            for (int tx = 0; tx < 3; tx++) {
                float xv = xp[(y + ty) * 30 + (xx + tx)];
                int tap = ty * 3 + tx;
                #pragma unroll
                for (int o = 0; o < 18; o++) off[o] = fmaf(xv, swo[o * 9 + tap], off[o]);
            }
        float s[9];
        #pragma unroll
        for (int j = 0; j < 9; j++) {
            float py = (float)y + (float)(j / 3 - 1) + off[2 * j];
            float px = (float)xx + (float)(j % 3 - 1) + off[2 * j + 1];
            float y0 = floorf(py), x0 = floorf(px);
            float wy1 = py - y0, wx1 = px - x0;
            float wy0 = 1.f - wy1, wx0 = 1.f - wx1;
            float acc = 0.f;
            #pragma unroll
            for (int cy = 0; cy < 2; cy++)
                #pragma unroll
                for (int cx = 0; cx < 2; cx++) {
                    float yy = y0 + (float)cy, xf = x0 + (float)cx;
                    bool valid = (yy >= 0.f) && (yy <= 27.f) && (xf >= 0.f) && (xf <= 27.f);
                    int yc = (int)fminf(fmaxf(yy, 0.f), 27.f);
                    int xc = (int)fminf(fmaxf(xf, 0.f), 27.f);
                    float g = valid ? xp[(yc + 1) * 30 + (xc + 1)] : 0.f;
                    float w = (cy ? wy1 : wy0) * (cx ? wx1 : wx0);
                    acc = fmaf(g, w, acc);
                }
            s[j] = acc;
        }
        size_t base = ((size_t)lb * 900 + (size_t)(y + 1) * 30 + (xx + 1)) * 32;
        #pragma unroll
        for (int c0 = 0; c0 < 32; c0 += 8) {
            float h[8];
            #pragma unroll
            for (int ci = 0; ci < 8; ci++) {
                int c = c0 + ci;
                float hv = sbd[c];
                #pragma unroll
                for (int j = 0; j < 9; j++) hv = fmaf(s[j], swd[c * 9 + j], hv);
                h[ci] = hv * ss1[c] + ssh[c];
            }
            uint4 q;
            q.x = pack2(h[0], h[1]); q.y = pack2(h[2], h[3]);
            q.z = pack2(h[4], h[5]); q.w = pack2(h[6], h[7]);
            *reinterpret_cast<uint4*>(&act1[base + c0]) = q;
        }
    }

    // zero padded borders of act1/act2/act3 for this image (116 border pixels)
    for (int i = tid; i < 116; i += 256) {
        int py, px;
        if (i < 30)      { py = 0;          px = i; }
        else if (i < 60) { py = 29;         px = i - 30; }
        else if (i < 88) { py = i - 60 + 1; px = 0; }
        else             { py = i - 88 + 1; px = 29; }
        size_t pix = (size_t)lb * 900 + (size_t)py * 30 + px;
        uint4 z = {0, 0, 0, 0};
        uint4* p1 = reinterpret_cast<uint4*>(&act1[pix * 32]);
        #pragma unroll
        for (int k = 0; k < 4; k++) p1[k] = z;
        uint4* p2 = reinterpret_cast<uint4*>(&act2[pix * 64]);
        #pragma unroll
        for (int k = 0; k < 8; k++) p2[k] = z;
        uint4* p3 = reinterpret_cast<uint4*>(&act3[pix * 128]);
        #pragma unroll
        for (int k = 0; k < 16; k++) p3[k] = z;
    }
}

// ---------------- conv 3x3 (implicit GEMM, MFMA bf16) ----------------
template<int CIN>
__device__ __forceinline__ int swz(int ofs) {
    if constexpr (CIN == 128) return (ofs >> 4) & 0x70;      // bits 8-10 -> 4-6
    else if constexpr (CIN == 64) return (ofs >> 3) & 0x70;  // bits 7-9  -> 4-6
    else return (ofs >> 2) & 0x30;                           // bits 6-7  -> 4-5
}

template<int CIN, int COUT, bool POOL, int MFW>
__device__ __forceinline__ void conv_body(
    const __hip_bfloat16* tile,
    const __hip_bfloat16* __restrict__ Wt,
    const float* __restrict__ bconv, const float* __restrict__ bnS,
    const float* __restrict__ bnB, __hip_bfloat16* __restrict__ aout,
    float* __restrict__ pooled, int lb, int gb, int rg, int lane, int mhalf, int nhalf)
{
    constexpr int NFW = COUT / 32;      // n-frags per wave
    const int l15 = lane & 15, kg = lane >> 4;
    const int nbase = nhalf * (NFW * 16) + l15;

    f32x4 acc[MFW][NFW] = {};

    for (int t = 0; t < 9; ++t) {
        const int ty = t / 3, tx = t % 3;
        #pragma unroll
        for (int kc = 0; kc < CIN; kc += 32) {
            bf16x8 bf[NFW];
            #pragma unroll
            for (int nf = 0; nf < NFW; ++nf) {
                const __hip_bfloat16* wp =
                    Wt + ((size_t)(t * COUT + nbase + nf * 16)) * CIN + kc + kg * 8;
                bf[nf] = *reinterpret_cast<const bf16x8*>(wp);
            }
            #pragma unroll
            for (int mf = 0; mf < MFW; ++mf) {
                int m = (mhalf * 4 + mf) * 16 + l15;
                int lr = m / 28 + ty;
                int lc = m % 28 + tx;
                int ba = ((lr * 30 + lc) * CIN + kc + kg * 8) * 2;
                ba ^= swz<CIN>(ba);
                bf16x8 af = *reinterpret_cast<const bf16x8*>(
                    reinterpret_cast<const char*>(tile) + ba);
                #pragma unroll
                for (int nf = 0; nf < NFW; ++nf)
                    acc[mf][nf] = __builtin_amdgcn_mfma_f32_16x16x32_bf16(
                        af, bf[nf], acc[mf][nf], 0, 0, 0);
            }
        }
    }

    if constexpr (!POOL) {
        #pragma unroll
        for (int mf = 0; mf < MFW; ++mf) {
            #pragma unroll
            for (int nf = 0; nf < NFW; ++nf) {
                int n = nbase + nf * 16;
                float bc = bconv[n], sc = bnS[n], sh = bnB[n];
                #pragma unroll
                for (int r = 0; r < 4; r++) {
                    int m = (mhalf * 4 + mf) * 16 + kg * 4 + r;
                    float y = acc[mf][nf][r] + bc;
                    y = fmaxf(y, 0.f);
                    y = y * sc + sh;
                    int oy = m / 28, ox = m % 28;
                    aout[((size_t)lb * 900 + (size_t)(rg * 4 + oy + 1) * 30 + (ox + 1)) * COUT + n]
                        = __float2bfloat16(y);
                }
            }
        }
    } else {
        #pragma unroll
        for (int nf = 0; nf < NFW; ++nf) {
            int n = nbase + nf * 16;
            float bc = bconv[n], sc = bnS[n], sh = bnB[n];
            float ps = 0.f;
            #pragma unroll
            for (int mf = 0; mf < MFW; ++mf)
                #pragma unroll
                for (int r = 0; r < 4; r++) {
                    float y = acc[mf][nf][r] + bc;
                    y = fmaxf(y, 0.f);
                    ps += y * sc + sh;
                }
            ps += __shfl_xor(ps, 16, 64);
            ps += __shfl_xor(ps, 32, 64);
            if (lane < 16) atomicAdd(&pooled[gb * COUT + n], ps);
        }
    }
}

template<int CIN, int COUT, bool POOL>
__global__ __launch_bounds__(256, 3) void conv_k(
    const __hip_bfloat16* __restrict__ ain,
    const __hip_bfloat16* __restrict__ Wt,
    const float* __restrict__ bconv,
    const float* __restrict__ bnS,
    const float* __restrict__ bnB,
    __hip_bfloat16* __restrict__ aout,
    float* __restrict__ pooled, int b0)
{
    __shared__ __align__(16) __hip_bfloat16 tile[180 * CIN];
    const int rg = blockIdx.x;   // 0..6 (4 output rows each)
    const int lb = blockIdx.y;   // chunk-local image
    const int tid = threadIdx.x;
    const int lane = tid & 63;
    const int wv = tid >> 6;
    const int mhalf = wv >> 1, nhalf = wv & 1;

    // stage 6 padded rows (rg*4 .. rg*4+5) x 30 x CIN, XOR-swizzled
    const char* src = reinterpret_cast<const char*>(
        ain + ((size_t)lb * 900 + (size_t)rg * 120) * CIN);
    constexpr int TB = 180 * CIN * 2;
    for (int ofs = tid * 16; ofs < TB; ofs += 4096) {
        uint4 v = *reinterpret_cast<const uint4*>(src + ofs);
        *reinterpret_cast<uint4*>(reinterpret_cast<char*>(tile) + (ofs ^ swz<CIN>(ofs))) = v;
    }
    __syncthreads();

    if (mhalf == 0)
        conv_body<CIN, COUT, POOL, 4>(tile, Wt, bconv, bnS, bnB, aout, pooled,
                                      lb, b0 + lb, rg, lane, mhalf, nhalf);
    else
        conv_body<CIN, COUT, POOL, 3>(tile, Wt, bconv, bnS, bnB, aout, pooled,
                                      lb, b0 + lb, rg, lane, mhalf, nhalf);
}

// ---------------- head: mean-pool scale + FC + log-softmax ----------------
__global__ __launch_bounds__(256) void head_k(
    const float* __restrict__ pooled, const float* __restrict__ wfc,
    const float* __restrict__ bfc, float* __restrict__ out)
{
    int b = blockIdx.x * 4 + (threadIdx.x >> 6);
    int lane = threadIdx.x & 63;
    float m0 = pooled[b * 128 + lane] * (1.f / 784.f);
    float m1 = pooled[b * 128 + 64 + lane] * (1.f / 784.f);
    float lg[10];
    #pragma unroll
    for (int k = 0; k < 10; k++) {
        float p = m0 * wfc[k * 128 + lane] + m1 * wfc[k * 128 + 64 + lane];
        #pragma unroll
        for (int s2 = 32; s2 >= 1; s2 >>= 1) p += __shfl_xor(p, s2, 64);
        lg[k] = p + bfc[k];
    }
    float mx = lg[0];
    #pragma unroll
    for (int k = 1; k < 10; k++) mx = fmaxf(mx, lg[k]);
    float se = 0.f;
    #pragma unroll
    for (int k = 0; k < 10; k++) se += expf(lg[k] - mx);
    float lse = mx + logf(se);
    #pragma unroll
    for (int k = 0; k < 10; k++)
        if (lane == k) out[b * 10 + k] = lg[k] - lse;
}

// ---------------- launch ----------------
extern "C" void kernel_launch(void* const* d_in, const int* in_sizes, int n_in,
                              void* d_out, int out_size, void* d_ws, size_t ws_size,
                              hipStream_t stream) {
    (void)in_sizes; (void)n_in; (void)out_size;
    const float* x     = (const float*)d_in[0];
    const float* w_off = (const float*)d_in[1];
    const float* b_off = (const float*)d_in[2];
    const float* w_dcn = (const float*)d_in[3];
    const float* b_dcn = (const float*)d_in[4];
    const float* w2    = (const float*)d_in[5];
    const float* b2    = (const float*)d_in[6];
    const float* w3    = (const float*)d_in[7];
    const float* b3    = (const float*)d_in[8];
    const float* w4    = (const float*)d_in[9];
    const float* b4    = (const float*)d_in[10];
    const float* w_fc  = (const float*)d_in[11];
    const float* b_fc  = (const float*)d_in[12];

    // Runtime chunk size: largest power-of-two divisor of 1024 whose chunk-local
    // activations + fixed tables fit in ws_size. (ws_size is constant across
    // calls, so the launch sequence is identical every call -> capture-safe.)
    int CH = 256;
    while (CH > 1 && (size_t)CH * ACT_PER_IMG + SZ_FIXED > ws_size) CH >>= 1;
    const int NCHUNK = 1024 / CH;

    char* ws = (char*)d_ws;
    const size_t szA1 = (size_t)CH * 57600;
    const size_t szA2 = (size_t)CH * 115200;
    const size_t szA3 = (size_t)CH * 230400;
    __hip_bfloat16* act1 = (__hip_bfloat16*)(ws);
    __hip_bfloat16* act2 = (__hip_bfloat16*)(ws + szA1);
    __hip_bfloat16* act3 = (__hip_bfloat16*)(ws + szA1 + szA2);
    float* pooled        = (float*)(ws + szA1 + szA2 + szA3);
    __hip_bfloat16* W2   = (__hip_bfloat16*)(ws + szA1 + szA2 + szA3 + SZ_POOL);
    __hip_bfloat16* W3   = (__hip_bfloat16*)((char*)W2 + SZ_W2);
    __hip_bfloat16* W4   = (__hip_bfloat16*)((char*)W3 + SZ_W3);
    float* bn            = (float*)((char*)W4 + SZ_W4);

    PrepArgs pa;
    pa.w2 = w2; pa.w3 = w3; pa.w4 = w4;
    pa.g1 = (const float*)d_in[13]; pa.b1 = (const float*)d_in[14];
    pa.m1 = (const float*)d_in[15]; pa.v1 = (const float*)d_in[16];
    pa.g2 = (const float*)d_in[17]; pa.b2 = (const float*)d_in[18];
    pa.m2 = (const float*)d_in[19]; pa.v2 = (const float*)d_in[20];
    pa.g3 = (const float*)d_in[21]; pa.b3 = (const float*)d_in[22];
    pa.m3 = (const float*)d_in[23]; pa.v3 = (const float*)d_in[24];
    pa.g4 = (const float*)d_in[25]; pa.b4 = (const float*)d_in[26];
    pa.m4 = (const float*)d_in[27]; pa.v4 = (const float*)d_in[28];
    pa.W2 = W2; pa.W3 = W3; pa.W4 = W4; pa.bn = bn;

    prep_k<<<938, 256, 0, stream>>>(pa);
    for (int c = 0; c < NCHUNK; ++c) {
        int b0 = c * CH;
        deform_k<<<CH, 256, 0, stream>>>(x, w_off, b_off, w_dcn, b_dcn, bn,
                                         act1, act2, act3, pooled, b0);
        conv_k<32, 64, false><<<dim3(7, CH), 256, 0, stream>>>(
            act1, W2, b2, bn + 64, bn + 128, act2, nullptr, b0);
        conv_k<64, 128, false><<<dim3(7, CH), 256, 0, stream>>>(
            act2, W3, b3, bn + 192, bn + 320, act3, nullptr, b0);
        conv_k<128, 128, true><<<dim3(7, CH), 256, 0, stream>>>(
            act3, W4, b4, bn + 448, bn + 576, nullptr, pooled, b0);
    }
    head_k<<<256, 256, 0, stream>>>(pooled, w_fc, b_fc, (float*)d_out);
}